// Round 5
// baseline (254.880 us; speedup 1.0000x reference)
//
#include <hip/hip_runtime.h>

#define BN_EPS 1e-5f

typedef unsigned short u16;
typedef __bf16 bf16x8 __attribute__((ext_vector_type(8)));
typedef float floatx4 __attribute__((ext_vector_type(4)));
typedef u16 u16x4 __attribute__((ext_vector_type(4)));
typedef u16 u16x8 __attribute__((ext_vector_type(8)));

__device__ __forceinline__ u16 f2bf(float f) {
    union { float f; unsigned int u; } v; v.f = f;
    unsigned int r = (v.u + 0x7fffu + ((v.u >> 16) & 1u)) >> 16;
    return (u16)r;
}

// async 16B global->LDS; lane i lands at (wave-uniform) dst + i*16.
__device__ __forceinline__ void gld16(const void* gsrc, void* ldst) {
    __builtin_amdgcn_global_load_lds(
        (const __attribute__((address_space(1))) unsigned int*)gsrc,
        (__attribute__((address_space(3))) unsigned int*)ldst, 16, 0, 0);
}

// ---------------------------------------------------------------- prep ----
__global__ __launch_bounds__(256) void prep_kernel(
    const float* __restrict__ wt, const float* __restrict__ wp,
    const float* __restrict__ wg, const float* __restrict__ wz,
    const float* __restrict__ g1, const float* __restrict__ b1,
    const float* __restrict__ m1, const float* __restrict__ v1,
    const float* __restrict__ g2, const float* __restrict__ b2,
    const float* __restrict__ m2, const float* __restrict__ v2,
    const float* __restrict__ g3, const float* __restrict__ b3,
    const float* __restrict__ m3, const float* __restrict__ v3,
    const float* __restrict__ g4, const float* __restrict__ b4,
    const float* __restrict__ m4, const float* __restrict__ v4,
    u16* __restrict__ W1bf, float* __restrict__ shift1,
    u16* __restrict__ Wzbf, float* __restrict__ shift4)
{
    int id = blockIdx.x * 256 + threadIdx.x;
    if (id < 384 * 256) {
        int r = id >> 8, c = id & 255;
        int grp = r >> 7, ch = r & 127;
        const float* wsrc = grp == 0 ? wt : (grp == 1 ? wp : wg);
        const float* gg = grp == 0 ? g1 : (grp == 1 ? g2 : g3);
        const float* bb = grp == 0 ? b1 : (grp == 1 ? b2 : b3);
        const float* mm = grp == 0 ? m1 : (grp == 1 ? m2 : m3);
        const float* vv = grp == 0 ? v1 : (grp == 1 ? v2 : v3);
        float scale = gg[ch] * rsqrtf(vv[ch] + BN_EPS);
        W1bf[id] = f2bf(wsrc[ch * 256 + c] * scale);
        if (c == 0) shift1[r] = bb[ch] - mm[ch] * scale;
    }
    if (id < 256 * 128) {
        int o = id >> 7;
        float scale = g4[o] * rsqrtf(v4[o] + BN_EPS);
        Wzbf[id] = f2bf(wz[id] * scale);
        if ((id & 127) == 0) shift4[o] = b4[o] - m4[o] * scale;
    }
}

// ------------------------------------------------------------------ xt ----
// x[n][c][s] fp32 -> xt[n][s][c] bf16.  Block: 64 s-rows x 256 c.
__global__ __launch_bounds__(256) void xt_kernel(
    const float* __restrict__ x, u16* __restrict__ xt)
{
    const int stile = blockIdx.x, n = blockIdx.y;
    const int t = threadIdx.x;
    __shared__ __align__(16) u16 lds[64 * 256];

    const float* xb = x + (size_t)n * 1048576 + stile * 64;
    const int crow0 = t >> 4, sf4 = t & 15;
#pragma unroll
    for (int i = 0; i < 16; ++i) {
        int c = crow0 + 16 * i;
        float4 v = *((const float4*)(xb + (size_t)c * 4096) + sf4);
        int cseg = c >> 3, cin = c & 7;
#pragma unroll
        for (int j = 0; j < 4; ++j) {
            int s = sf4 * 4 + j;
            int csw = (cseg & ~7) | ((cseg ^ (s >> 2)) & 7);
            lds[s * 256 + csw * 8 + cin] = f2bf(((const float*)&v)[j]);
        }
    }
    __syncthreads();

    const int so = t >> 2, c4 = t & 3;
    u16* ob = xt + (size_t)n * 1048576 + (size_t)(stile * 64 + so) * 256;
#pragma unroll
    for (int i = 0; i < 8; ++i) {
        int cseg = c4 + 4 * i;
        int csw = (cseg & ~7) | ((cseg ^ (so >> 2)) & 7);
        *(u16x8*)(ob + cseg * 8) = *(const u16x8*)(lds + so * 256 + csw * 8);
    }
}

// --------------------------------------------------------------- gemm1 ----
// Merged: one block computes ALL 384 output channels for a 128-s tile.
// A = W1 (384x64 chunk, 48KB), B = xt (128x64 chunk, 16KB); xt read ONCE.
__global__ __launch_bounds__(256, 2) void gemm1_kernel(
    const u16* __restrict__ xt, const u16* __restrict__ W1,
    const float* __restrict__ shift1,
    u16* __restrict__ theta_sm, u16* __restrict__ pg)
{
    const int st = blockIdx.x, n = blockIdx.y;
    const int tid = threadIdx.x;
    const int w = tid >> 6, lane = tid & 63;
    const int quad = lane >> 4, l16 = lane & 15;

    __shared__ __align__(16) u16 ldsA[384 * 64];  // W1 chunk, xor-swizzled
    __shared__ __align__(16) u16 ldsB[128 * 64];  // xt chunk, xor-swizzled

    floatx4 acc[3][2][8];
#pragma unroll
    for (int m = 0; m < 3; ++m)
#pragma unroll
        for (int i = 0; i < 2; ++i)
#pragma unroll
            for (int j = 0; j < 8; ++j) acc[m][i][j] = floatx4{0.f, 0.f, 0.f, 0.f};

    const u16* xb = xt + (size_t)n * 1048576 + (size_t)st * 128 * 256;

    for (int kc = 0; kc < 4; ++kc) {
        // stage A: W1[0..384][kc*64..+64] — 48 ops, 12/wave
#pragma unroll
        for (int i = 0; i < 12; ++i) {
            int op = w * 12 + i;
            int r = op * 8 + (lane >> 3);
            int lseg = (lane & 7) ^ (r & 7);
            gld16(W1 + (size_t)r * 256 + kc * 64 + lseg * 8, ldsA + op * 512);
        }
        // stage B: xt tile — 16 ops, 4/wave
#pragma unroll
        for (int i = 0; i < 4; ++i) {
            int op = w * 4 + i;
            int r = op * 8 + (lane >> 3);
            int lseg = (lane & 7) ^ (r & 7);
            gld16(xb + (size_t)r * 256 + kc * 64 + lseg * 8, ldsB + op * 512);
        }
        __syncthreads();

#pragma unroll
        for (int kk = 0; kk < 2; ++kk) {
#pragma unroll
            for (int g = 0; g < 2; ++g) {
                bf16x8 b[4];
#pragma unroll
                for (int nj = 0; nj < 4; ++nj) {
                    int s = (g * 4 + nj) * 16 + l16;
                    int phys = (kk * 4 + quad) ^ (s & 7);
                    b[nj] = *(const bf16x8*)(ldsB + s * 64 + phys * 8);
                }
#pragma unroll
                for (int mt = 0; mt < 3; ++mt) {
                    bf16x8 a0, a1;
                    {
                        int r = mt * 128 + w * 32 + l16;
                        int phys = (kk * 4 + quad) ^ (r & 7);
                        a0 = *(const bf16x8*)(ldsA + r * 64 + phys * 8);
                        int r2 = r + 16;
                        int phys2 = (kk * 4 + quad) ^ (r2 & 7);
                        a1 = *(const bf16x8*)(ldsA + r2 * 64 + phys2 * 8);
                    }
#pragma unroll
                    for (int nj = 0; nj < 4; ++nj) {
                        acc[mt][0][g * 4 + nj] = __builtin_amdgcn_mfma_f32_16x16x32_bf16(
                            a0, b[nj], acc[mt][0][g * 4 + nj], 0, 0, 0);
                        acc[mt][1][g * 4 + nj] = __builtin_amdgcn_mfma_f32_16x16x32_bf16(
                            a1, b[nj], acc[mt][1][g * 4 + nj], 0, 0, 0);
                    }
                }
            }
        }
        __syncthreads();
    }

    // epilogue: mt=0 -> theta_sm [s][c'] (8B stores); mt=1,2 -> pg [oc'][s]
#pragma unroll
    for (int mi = 0; mi < 2; ++mi) {
        int ocb = w * 32 + mi * 16 + quad * 4;
        float sh0 = shift1[ocb + 0], sh1 = shift1[ocb + 1];
        float sh2 = shift1[ocb + 2], sh3 = shift1[ocb + 3];
#pragma unroll
        for (int ni = 0; ni < 8; ++ni) {
            int s = st * 128 + ni * 16 + l16;
            float v0 = acc[0][mi][ni][0] + sh0, v1 = acc[0][mi][ni][1] + sh1;
            float v2 = acc[0][mi][ni][2] + sh2, v3 = acc[0][mi][ni][3] + sh3;
            u16x4 pk;
            pk[0] = f2bf(v0 > 0.f ? v0 : 0.f);
            pk[1] = f2bf(v1 > 0.f ? v1 : 0.f);
            pk[2] = f2bf(v2 > 0.f ? v2 : 0.f);
            pk[3] = f2bf(v3 > 0.f ? v3 : 0.f);
            *(u16x4*)(theta_sm + (size_t)n * 524288 + (size_t)s * 128 + ocb) = pk;
        }
    }
#pragma unroll
    for (int mt = 1; mt < 3; ++mt)
#pragma unroll
        for (int mi = 0; mi < 2; ++mi)
#pragma unroll
            for (int r = 0; r < 4; ++r) {
                int oc = mt * 128 + w * 32 + mi * 16 + quad * 4 + r;
                int prow = (mt - 1) * 128 + w * 32 + mi * 16 + quad * 4 + r;
                float sh = shift1[oc];
#pragma unroll
                for (int ni = 0; ni < 8; ++ni) {
                    int s = st * 128 + ni * 16 + l16;
                    float val = acc[mt][mi][ni][r] + sh;
                    val = val > 0.f ? val : 0.f;
                    pg[(size_t)n * 1048576 + (size_t)prow * 4096 + s] = f2bf(val);
                }
            }
}

// --------------------------------------------------------------- gemm2 ----
// partials[n][kc][d][c] = sum_{s in 512-chunk kc} g[d][s]*phi[c][s]  (split-K=8)
__global__ __launch_bounds__(256) void gemm2_kernel(
    const u16* __restrict__ pg, float* __restrict__ partials)
{
    const int kc = blockIdx.x, n = blockIdx.y;   // kc 0..7
    const int tid = threadIdx.x;
    const int w = tid >> 6, lane = tid & 63;
    const int quad = lane >> 4, l16 = lane & 15;

    __shared__ __align__(16) u16 ldsG[128 * 64];
    __shared__ __align__(16) u16 ldsP[128 * 64];

    floatx4 acc[2][8];
#pragma unroll
    for (int i = 0; i < 2; ++i)
#pragma unroll
        for (int j = 0; j < 8; ++j) acc[i][j] = floatx4{0.f, 0.f, 0.f, 0.f};

    const u16* base = pg + (size_t)n * 1048576;  // phi rows 0..127, g 128..255

    for (int ch = 0; ch < 8; ++ch) {
        int s0 = kc * 512 + ch * 64;
#pragma unroll
        for (int i = 0; i < 4; ++i) {
            int op = w * 4 + i;
            int r = op * 8 + (lane >> 3);
            int lseg = (lane & 7) ^ (r & 7);
            gld16(base + (size_t)(128 + r) * 4096 + s0 + lseg * 8, ldsG + op * 512);
            gld16(base + (size_t)r * 4096 + s0 + lseg * 8, ldsP + op * 512);
        }
        __syncthreads();

#pragma unroll
        for (int kk = 0; kk < 2; ++kk) {
            bf16x8 a[2];
#pragma unroll
            for (int mi = 0; mi < 2; ++mi) {
                int r = w * 32 + mi * 16 + l16;
                int phys = (kk * 4 + quad) ^ (r & 7);
                a[mi] = *(const bf16x8*)(ldsG + r * 64 + phys * 8);
            }
#pragma unroll
            for (int ci = 0; ci < 8; ++ci) {
                int r = ci * 16 + l16;
                int phys = (kk * 4 + quad) ^ (r & 7);
                bf16x8 b = *(const bf16x8*)(ldsP + r * 64 + phys * 8);
#pragma unroll
                for (int mi = 0; mi < 2; ++mi)
                    acc[mi][ci] = __builtin_amdgcn_mfma_f32_16x16x32_bf16(
                        a[mi], b, acc[mi][ci], 0, 0, 0);
            }
        }
        __syncthreads();
    }

    float* outp = partials + (size_t)(n * 8 + kc) * 16384;
#pragma unroll
    for (int mi = 0; mi < 2; ++mi)
#pragma unroll
        for (int r = 0; r < 4; ++r) {
            int d = w * 32 + mi * 16 + quad * 4 + r;
#pragma unroll
            for (int ci = 0; ci < 8; ++ci)
                outp[d * 128 + ci * 16 + l16] = acc[mi][ci][r];
        }
}

// ----------------------------------------------------------- kv reduce ----
__global__ __launch_bounds__(256) void kv_reduce_kernel(
    const float* __restrict__ partials, u16* __restrict__ kvT)
{
    int n = blockIdx.y;
    int f4 = blockIdx.x * 256 + threadIdx.x;    // 0..4095
    const float4* p4 = (const float4*)partials;
    float4 s = {0.f, 0.f, 0.f, 0.f};
#pragma unroll
    for (int kc = 0; kc < 8; ++kc) {
        float4 v = p4[(size_t)(n * 8 + kc) * 4096 + f4];
        s.x += v.x; s.y += v.y; s.z += v.z; s.w += v.w;
    }
    u16x4 o; o[0] = f2bf(s.x); o[1] = f2bf(s.y); o[2] = f2bf(s.z); o[3] = f2bf(s.w);
    *(u16x4*)(kvT + (size_t)n * 16384 + f4 * 4) = o;
}

// --------------------------------------------------------------- gemm3 ----
// out_sd[n][s][d] = sum_c theta_sm[s][c] * kvT[d][c] — single-shot staging
// (full K=128 tiles, 16-segment xor swizzle, one barrier).
__global__ __launch_bounds__(256) void gemm3_kernel(
    const u16* __restrict__ theta_sm, const u16* __restrict__ kvT,
    u16* __restrict__ out_sd)
{
    const int st = blockIdx.x, n = blockIdx.y;
    const int tid = threadIdx.x;
    const int w = tid >> 6, lane = tid & 63;
    const int quad = lane >> 4, l16 = lane & 15;

    __shared__ __align__(16) u16 ldsT[128 * 128];
    __shared__ __align__(16) u16 ldsK[128 * 128];

    floatx4 acc[2][8];
#pragma unroll
    for (int i = 0; i < 2; ++i)
#pragma unroll
        for (int j = 0; j < 8; ++j) acc[i][j] = floatx4{0.f, 0.f, 0.f, 0.f};

    const u16* tbase = theta_sm + (size_t)n * 524288 + (size_t)st * 128 * 128;
    const u16* kbase = kvT + (size_t)n * 16384;

    // 32 ops per operand (1KB each = 4 rows of 256B); 8/wave each
#pragma unroll
    for (int i = 0; i < 8; ++i) {
        int op = w * 8 + i;
        int r = op * 4 + (lane >> 4);
        int g = (lane & 15) ^ (r & 15);
        gld16(tbase + (size_t)r * 128 + g * 8, ldsT + op * 512);
        gld16(kbase + (size_t)r * 128 + g * 8, ldsK + op * 512);
    }
    __syncthreads();

#pragma unroll
    for (int kk = 0; kk < 4; ++kk) {
        bf16x8 a[2];
#pragma unroll
        for (int mi = 0; mi < 2; ++mi) {
            int r = w * 32 + mi * 16 + l16;
            int phys = (kk * 4 + quad) ^ (r & 15);
            a[mi] = *(const bf16x8*)(ldsT + r * 128 + phys * 8);
        }
#pragma unroll
        for (int di = 0; di < 8; ++di) {
            int r = di * 16 + l16;
            int phys = (kk * 4 + quad) ^ (r & 15);
            bf16x8 b = *(const bf16x8*)(ldsK + r * 128 + phys * 8);
#pragma unroll
            for (int mi = 0; mi < 2; ++mi)
                acc[mi][di] = __builtin_amdgcn_mfma_f32_16x16x32_bf16(
                    a[mi], b, acc[mi][di], 0, 0, 0);
        }
    }

#pragma unroll
    for (int mi = 0; mi < 2; ++mi)
#pragma unroll
        for (int r = 0; r < 4; ++r) {
            int s = st * 128 + w * 32 + mi * 16 + quad * 4 + r;
#pragma unroll
            for (int di = 0; di < 8; ++di)
                out_sd[(size_t)n * 524288 + (size_t)s * 128 + di * 16 + l16] =
                    f2bf(acc[mi][di][r]);
        }
}

// --------------------------------------------------------------- gemm4 ----
__device__ __forceinline__ int addsw(int seg, int s) {
    return (seg + (s & 7) + ((s >> 3) & 7)) & 7;
}

__global__ __launch_bounds__(256) void gemm4_kernel(
    const u16* __restrict__ out_sd, const u16* __restrict__ Wz,
    const float* __restrict__ shift4, const float* __restrict__ x,
    float* __restrict__ out)
{
    const int st = blockIdx.x, ot = blockIdx.y, n = blockIdx.z;
    const int tid = threadIdx.x;
    const int w = tid >> 6, lane = tid & 63;
    const int quad = lane >> 4, l16 = lane & 15;

    __shared__ __align__(16) u16 ldsY[128 * 64];
    __shared__ __align__(16) u16 ldsW[128 * 64];

    floatx4 acc[2][8];
#pragma unroll
    for (int i = 0; i < 2; ++i)
#pragma unroll
        for (int j = 0; j < 8; ++j) acc[i][j] = floatx4{0.f, 0.f, 0.f, 0.f};

    const int sl = tid & 15;
    const int cg = tid >> 4;
    const u16* ybase = out_sd + (size_t)n * 524288 + st * 128;
    unsigned int* ldsYdw = (unsigned int*)ldsY;

    u16x8 yv0[2], yv1[2];
#pragma unroll
    for (int p = 0; p < 2; ++p) {
        int c0 = 2 * cg + 32 * p;
        yv0[p] = *(const u16x8*)(ybase + (size_t)c0 * 4096 + 8 * sl);
        yv1[p] = *(const u16x8*)(ybase + (size_t)(c0 + 1) * 4096 + 8 * sl);
    }

    for (int kc = 0; kc < 2; ++kc) {
#pragma unroll
        for (int p = 0; p < 2; ++p) {
            int cp = cg + 16 * p, slog = cp >> 2, dwin = cp & 3;
#pragma unroll
            for (int j = 0; j < 8; ++j) {
                int s = 8 * sl + j;
                unsigned int pk = (unsigned int)yv0[p][j] | ((unsigned int)yv1[p][j] << 16);
                ldsYdw[s * 32 + addsw(slog, s) * 4 + dwin] = pk;
            }
        }
#pragma unroll
        for (int i = 0; i < 4; ++i) {
            int op = w * 4 + i;
            int r = op * 8 + (lane >> 3);
            int lseg = (lane & 7) ^ (r & 7);
            gld16(Wz + (size_t)(ot * 128 + r) * 128 + kc * 64 + lseg * 8, ldsW + op * 512);
        }
        if (kc < 1) {
#pragma unroll
            for (int p = 0; p < 2; ++p) {
                int c0 = 2 * cg + 32 * p;
                yv0[p] = *(const u16x8*)(ybase + (size_t)(64 + c0) * 4096 + 8 * sl);
                yv1[p] = *(const u16x8*)(ybase + (size_t)(64 + c0 + 1) * 4096 + 8 * sl);
            }
        }
        __syncthreads();

#pragma unroll
        for (int kk = 0; kk < 2; ++kk) {
            bf16x8 a[2];
#pragma unroll
            for (int mi = 0; mi < 2; ++mi) {
                int r = w * 32 + mi * 16 + l16;
                int phys = (kk * 4 + quad) ^ (r & 7);
                a[mi] = *(const bf16x8*)(ldsW + r * 64 + phys * 8);
            }
#pragma unroll
            for (int ni = 0; ni < 8; ++ni) {
                int s = ni * 16 + l16;
                int phys = addsw(kk * 4 + quad, s);
                bf16x8 b = *(const bf16x8*)(ldsY + s * 64 + phys * 8);
#pragma unroll
                for (int mi = 0; mi < 2; ++mi)
                    acc[mi][ni] = __builtin_amdgcn_mfma_f32_16x16x32_bf16(
                        a[mi], b, acc[mi][ni], 0, 0, 0);
            }
        }
        __syncthreads();
    }

#pragma unroll
    for (int mi = 0; mi < 2; ++mi)
#pragma unroll
        for (int r = 0; r < 4; ++r) {
            int o = ot * 128 + w * 32 + mi * 16 + quad * 4 + r;
            float sh = shift4[o];
#pragma unroll
            for (int ni = 0; ni < 8; ++ni) {
                int s2 = st * 128 + ni * 16 + l16;
                size_t idx = ((size_t)n * 256 + o) * 4096 + s2;
                float val = acc[mi][ni][r] + sh + x[idx];
                out[idx] = val > 0.f ? val : 0.f;
            }
        }
}

// -------------------------------------------------------------- launch ----
extern "C" void kernel_launch(void* const* d_in, const int* in_sizes, int n_in,
                              void* d_out, int out_size, void* d_ws, size_t ws_size,
                              hipStream_t stream)
{
    const float* x  = (const float*)d_in[0];
    const float* wt = (const float*)d_in[1];
    const float* wp = (const float*)d_in[2];
    const float* wg = (const float*)d_in[3];
    const float* wz = (const float*)d_in[4];
    const float* bn[16];
    for (int i = 0; i < 16; ++i) bn[i] = (const float*)d_in[5 + i];

    char* ws = (char*)d_ws;
    u16*   W1bf     = (u16*)  (ws + 0);          // 196608
    float* shift1   = (float*)(ws + 196608);     // 1536
    u16*   Wzbf     = (u16*)  (ws + 198144);     // 65536
    float* shift4   = (float*)(ws + 263680);     // 1024
    u16*   xt       = (u16*)  (ws + 264704);     // 33554432 (dead after gemm1)
    float* partials = (float*)(ws + 264704);     // 8388608 (overlays xt)
    u16*   theta_sm = (u16*)  (ws + 33819136);   // 16777216
    u16*   pg       = (u16*)  (ws + 50596352);   // 33554432 (dead after gemm2)
    u16*   out_sd   = (u16*)  (ws + 50596352);   // 16777216 (overlays pg)
    u16*   kvT      = (u16*)  (ws + 84150784 - 524288);  // 524288
    float* out = (float*)d_out;

    prep_kernel<<<384, 256, 0, stream>>>(
        wt, wp, wg, wz,
        bn[0], bn[1], bn[2], bn[3],
        bn[4], bn[5], bn[6], bn[7],
        bn[8], bn[9], bn[10], bn[11],
        bn[12], bn[13], bn[14], bn[15],
        W1bf, shift1, Wzbf, shift4);

    xt_kernel<<<dim3(64, 16), 256, 0, stream>>>(x, xt);
    gemm1_kernel<<<dim3(32, 16), 256, 0, stream>>>(xt, W1bf, shift1, theta_sm, pg);
    gemm2_kernel<<<dim3(8, 16), 256, 0, stream>>>(pg, partials);
    kv_reduce_kernel<<<dim3(16, 16), 256, 0, stream>>>(partials, kvT);
    gemm3_kernel<<<dim3(32, 16), 256, 0, stream>>>(theta_sm, kvT, out_sd);
    gemm4_kernel<<<dim3(32, 2, 16), 256, 0, stream>>>(out_sd, Wzbf, shift4, x, out);
}

// Round 6
// 229.890 us; speedup vs baseline: 1.1087x; 1.1087x over previous
//
#include <hip/hip_runtime.h>

#define BN_EPS 1e-5f

typedef unsigned short u16;
typedef __bf16 bf16x8 __attribute__((ext_vector_type(8)));
typedef float floatx4 __attribute__((ext_vector_type(4)));
typedef u16 u16x4 __attribute__((ext_vector_type(4)));
typedef u16 u16x8 __attribute__((ext_vector_type(8)));

__device__ __forceinline__ u16 f2bf(float f) {
    union { float f; unsigned int u; } v; v.f = f;
    unsigned int r = (v.u + 0x7fffu + ((v.u >> 16) & 1u)) >> 16;
    return (u16)r;
}

// async 16B global->LDS; lane i lands at (wave-uniform) dst + i*16.
__device__ __forceinline__ void gld16(const void* gsrc, void* ldst) {
    __builtin_amdgcn_global_load_lds(
        (const __attribute__((address_space(1))) unsigned int*)gsrc,
        (__attribute__((address_space(3))) unsigned int*)ldst, 16, 0, 0);
}

// ---------------------------------------------------------------- prep ----
__global__ __launch_bounds__(256) void prep_kernel(
    const float* __restrict__ wt, const float* __restrict__ wp,
    const float* __restrict__ wg, const float* __restrict__ wz,
    const float* __restrict__ g1, const float* __restrict__ b1,
    const float* __restrict__ m1, const float* __restrict__ v1,
    const float* __restrict__ g2, const float* __restrict__ b2,
    const float* __restrict__ m2, const float* __restrict__ v2,
    const float* __restrict__ g3, const float* __restrict__ b3,
    const float* __restrict__ m3, const float* __restrict__ v3,
    const float* __restrict__ g4, const float* __restrict__ b4,
    const float* __restrict__ m4, const float* __restrict__ v4,
    u16* __restrict__ W1bf, float* __restrict__ shift1,
    u16* __restrict__ Wzbf, float* __restrict__ shift4)
{
    int id = blockIdx.x * 256 + threadIdx.x;
    if (id < 384 * 256) {
        int r = id >> 8, c = id & 255;
        int grp = r >> 7, ch = r & 127;
        const float* wsrc = grp == 0 ? wt : (grp == 1 ? wp : wg);
        const float* gg = grp == 0 ? g1 : (grp == 1 ? g2 : g3);
        const float* bb = grp == 0 ? b1 : (grp == 1 ? b2 : b3);
        const float* mm = grp == 0 ? m1 : (grp == 1 ? m2 : m3);
        const float* vv = grp == 0 ? v1 : (grp == 1 ? v2 : v3);
        float scale = gg[ch] * rsqrtf(vv[ch] + BN_EPS);
        W1bf[id] = f2bf(wsrc[ch * 256 + c] * scale);
        if (c == 0) shift1[r] = bb[ch] - mm[ch] * scale;
    }
    if (id < 256 * 128) {
        int o = id >> 7;
        float scale = g4[o] * rsqrtf(v4[o] + BN_EPS);
        Wzbf[id] = f2bf(wz[id] * scale);
        if ((id & 127) == 0) shift4[o] = b4[o] - m4[o] * scale;
    }
}

// ------------------------------------------------------------------ xt ----
// x[n][c][s] fp32 -> xt[n][s][c] bf16.  Block: 64 s-rows x 256 c.
__global__ __launch_bounds__(256) void xt_kernel(
    const float* __restrict__ x, u16* __restrict__ xt)
{
    const int stile = blockIdx.x, n = blockIdx.y;
    const int t = threadIdx.x;
    __shared__ __align__(16) u16 lds[64 * 256];

    const float* xb = x + (size_t)n * 1048576 + stile * 64;
    const int crow0 = t >> 4, sf4 = t & 15;
#pragma unroll
    for (int i = 0; i < 16; ++i) {
        int c = crow0 + 16 * i;
        float4 v = *((const float4*)(xb + (size_t)c * 4096) + sf4);
        int cseg = c >> 3, cin = c & 7;
#pragma unroll
        for (int j = 0; j < 4; ++j) {
            int s = sf4 * 4 + j;
            int csw = (cseg & ~7) | ((cseg ^ (s >> 2)) & 7);
            lds[s * 256 + csw * 8 + cin] = f2bf(((const float*)&v)[j]);
        }
    }
    __syncthreads();

    const int so = t >> 2, c4 = t & 3;
    u16* ob = xt + (size_t)n * 1048576 + (size_t)(stile * 64 + so) * 256;
#pragma unroll
    for (int i = 0; i < 8; ++i) {
        int cseg = c4 + 4 * i;
        int csw = (cseg & ~7) | ((cseg ^ (so >> 2)) & 7);
        *(u16x8*)(ob + cseg * 8) = *(const u16x8*)(lds + so * 256 + csw * 8);
    }
}

// --------------------------------------------------------------- gemm1 ----
// Split-mt (R4 structure): A = W1 (k-major), B = xt[s][c] (k-major).
// mt=0: theta -> theta_sm[n][s][c'] via LDS-staged flat coalesced stores;
// mt=1,2: phi/g -> pg[n][oc'][s] direct stores (measured amplification-free).
__global__ __launch_bounds__(256) void gemm1_kernel(
    const u16* __restrict__ xt, const u16* __restrict__ W1,
    const float* __restrict__ shift1,
    u16* __restrict__ theta_sm, u16* __restrict__ pg)
{
    const int st = blockIdx.x, mt = blockIdx.y, n = blockIdx.z;
    const int tid = threadIdx.x;
    const int w = tid >> 6, lane = tid & 63;
    const int quad = lane >> 4, l16 = lane & 15;

    __shared__ __align__(16) u16 lds[128 * 128];   // 32KB: A(16K) + B(16K), reused by epilogue
    u16* ldsA = lds;
    u16* ldsB = lds + 128 * 64;

    floatx4 acc[2][8];
#pragma unroll
    for (int i = 0; i < 2; ++i)
#pragma unroll
        for (int j = 0; j < 8; ++j) acc[i][j] = floatx4{0.f, 0.f, 0.f, 0.f};

    const u16* xb = xt + (size_t)n * 1048576 + (size_t)st * 128 * 256;

    for (int kc = 0; kc < 4; ++kc) {
#pragma unroll
        for (int i = 0; i < 4; ++i) {
            int op = w * 4 + i;
            int r = op * 8 + (lane >> 3);
            int lseg = (lane & 7) ^ (r & 7);
            gld16(W1 + (size_t)(mt * 128 + r) * 256 + kc * 64 + lseg * 8,
                  ldsA + op * 512);
            gld16(xb + (size_t)r * 256 + kc * 64 + lseg * 8,
                  ldsB + op * 512);
        }
        __syncthreads();

#pragma unroll
        for (int kk = 0; kk < 2; ++kk) {
            bf16x8 a[2];
#pragma unroll
            for (int mi = 0; mi < 2; ++mi) {
                int r = w * 32 + mi * 16 + l16;
                int phys = (kk * 4 + quad) ^ (r & 7);
                a[mi] = *(const bf16x8*)(ldsA + r * 64 + phys * 8);
            }
#pragma unroll
            for (int ni = 0; ni < 8; ++ni) {
                int s = ni * 16 + l16;
                int phys = (kk * 4 + quad) ^ (s & 7);
                bf16x8 b = *(const bf16x8*)(ldsB + s * 64 + phys * 8);
#pragma unroll
                for (int mi = 0; mi < 2; ++mi)
                    acc[mi][ni] = __builtin_amdgcn_mfma_f32_16x16x32_bf16(
                        a[mi], b, acc[mi][ni], 0, 0, 0);
            }
        }
        __syncthreads();
    }

    if (mt == 0) {
        // Phase 1: D-tile -> LDS [s_local][c] (256B rows, xor-seg swizzle).
        // Lane value (mi,ni,r): c = w*32+mi*16+quad*4+r, s_local = ni*16+l16.
#pragma unroll
        for (int mi = 0; mi < 2; ++mi) {
            int cb = w * 32 + mi * 16 + quad * 4;
            int seg = w * 2 + mi;                     // 32B segment index
            float sh0 = shift1[cb + 0], sh1 = shift1[cb + 1];
            float sh2 = shift1[cb + 2], sh3 = shift1[cb + 3];
#pragma unroll
            for (int ni = 0; ni < 8; ++ni) {
                int sl = ni * 16 + l16;
                float v0 = acc[mi][ni][0] + sh0, v1 = acc[mi][ni][1] + sh1;
                float v2 = acc[mi][ni][2] + sh2, v3 = acc[mi][ni][3] + sh3;
                u16x4 pk;
                pk[0] = f2bf(v0 > 0.f ? v0 : 0.f);
                pk[1] = f2bf(v1 > 0.f ? v1 : 0.f);
                pk[2] = f2bf(v2 > 0.f ? v2 : 0.f);
                pk[3] = f2bf(v3 > 0.f ? v3 : 0.f);
                *(u16x4*)(lds + sl * 128 + ((seg ^ (sl & 7)) * 16) + quad * 4) = pk;
            }
        }
        __syncthreads();
        // Phase 2: flat 32KB copy LDS -> theta_sm (tile is contiguous), 16B/lane.
        u16* gbase = theta_sm + (size_t)n * 524288 + (size_t)st * 128 * 128;
#pragma unroll
        for (int k = 0; k < 8; ++k) {
            int f = tid + k * 256;        // 16B-unit index, 0..2047
            int row = f >> 4;
            int u = f & 15;
            int seg = u >> 1, half = u & 1;
            *(u16x8*)(gbase + f * 8) =
                *(const u16x8*)(lds + row * 128 + ((seg ^ (row & 7)) * 16) + half * 8);
        }
    } else {
#pragma unroll
        for (int mi = 0; mi < 2; ++mi)
#pragma unroll
            for (int r = 0; r < 4; ++r) {
                int oc = mt * 128 + w * 32 + mi * 16 + quad * 4 + r;
                int prow = (mt - 1) * 128 + w * 32 + mi * 16 + quad * 4 + r;
                float sh = shift1[oc];
#pragma unroll
                for (int ni = 0; ni < 8; ++ni) {
                    int s = st * 128 + ni * 16 + l16;
                    float val = acc[mi][ni][r] + sh;
                    val = val > 0.f ? val : 0.f;
                    pg[(size_t)n * 1048576 + (size_t)prow * 4096 + s] = f2bf(val);
                }
            }
    }
}

// --------------------------------------------------------------- gemm2 ----
// partials[n][kc][d][c] = sum_{s in 128-chunk kc} g[d][s]*phi[c][s] (split-K=32)
__global__ __launch_bounds__(256) void gemm2_kernel(
    const u16* __restrict__ pg, float* __restrict__ partials)
{
    const int kc = blockIdx.x, n = blockIdx.y;   // kc 0..31
    const int tid = threadIdx.x;
    const int w = tid >> 6, lane = tid & 63;
    const int quad = lane >> 4, l16 = lane & 15;

    __shared__ __align__(16) u16 ldsG[128 * 64];
    __shared__ __align__(16) u16 ldsP[128 * 64];

    floatx4 acc[2][8];
#pragma unroll
    for (int i = 0; i < 2; ++i)
#pragma unroll
        for (int j = 0; j < 8; ++j) acc[i][j] = floatx4{0.f, 0.f, 0.f, 0.f};

    const u16* base = pg + (size_t)n * 1048576;  // phi rows 0..127, g 128..255

    for (int ch = 0; ch < 2; ++ch) {
        int s0 = kc * 128 + ch * 64;
#pragma unroll
        for (int i = 0; i < 4; ++i) {
            int op = w * 4 + i;
            int r = op * 8 + (lane >> 3);
            int lseg = (lane & 7) ^ (r & 7);
            gld16(base + (size_t)(128 + r) * 4096 + s0 + lseg * 8, ldsG + op * 512);
            gld16(base + (size_t)r * 4096 + s0 + lseg * 8, ldsP + op * 512);
        }
        __syncthreads();

#pragma unroll
        for (int kk = 0; kk < 2; ++kk) {
            bf16x8 a[2];
#pragma unroll
            for (int mi = 0; mi < 2; ++mi) {
                int r = w * 32 + mi * 16 + l16;
                int phys = (kk * 4 + quad) ^ (r & 7);
                a[mi] = *(const bf16x8*)(ldsG + r * 64 + phys * 8);
            }
#pragma unroll
            for (int ci = 0; ci < 8; ++ci) {
                int r = ci * 16 + l16;
                int phys = (kk * 4 + quad) ^ (r & 7);
                bf16x8 b = *(const bf16x8*)(ldsP + r * 64 + phys * 8);
#pragma unroll
                for (int mi = 0; mi < 2; ++mi)
                    acc[mi][ci] = __builtin_amdgcn_mfma_f32_16x16x32_bf16(
                        a[mi], b, acc[mi][ci], 0, 0, 0);
            }
        }
        __syncthreads();
    }

    float* outp = partials + (size_t)(n * 32 + kc) * 16384;
#pragma unroll
    for (int mi = 0; mi < 2; ++mi)
#pragma unroll
        for (int r = 0; r < 4; ++r) {
            int d = w * 32 + mi * 16 + quad * 4 + r;
#pragma unroll
            for (int ci = 0; ci < 8; ++ci)
                outp[d * 128 + ci * 16 + l16] = acc[mi][ci][r];
        }
}

// ----------------------------------------------------------- kv reduce ----
__global__ __launch_bounds__(256) void kv_reduce_kernel(
    const float* __restrict__ partials, u16* __restrict__ kvT)
{
    int n = blockIdx.y;
    int f4 = blockIdx.x * 256 + threadIdx.x;    // 0..4095
    const float4* p4 = (const float4*)partials;
    float4 s = {0.f, 0.f, 0.f, 0.f};
#pragma unroll
    for (int kc = 0; kc < 32; ++kc) {
        float4 v = p4[(size_t)(n * 32 + kc) * 4096 + f4];
        s.x += v.x; s.y += v.y; s.z += v.z; s.w += v.w;
    }
    u16x4 o; o[0] = f2bf(s.x); o[1] = f2bf(s.y); o[2] = f2bf(s.z); o[3] = f2bf(s.w);
    *(u16x4*)(kvT + (size_t)n * 16384 + f4 * 4) = o;
}

// --------------------------------------------------------------- gemm3 ----
// out_sd[n][s][d] = sum_c theta_sm[s][c] * kvT[d][c] — pure dual-gld16.
__global__ __launch_bounds__(256) void gemm3_kernel(
    const u16* __restrict__ theta_sm, const u16* __restrict__ kvT,
    u16* __restrict__ out_sd)
{
    const int st = blockIdx.x, n = blockIdx.y;
    const int tid = threadIdx.x;
    const int w = tid >> 6, lane = tid & 63;
    const int quad = lane >> 4, l16 = lane & 15;

    __shared__ __align__(16) u16 ldsT[128 * 64];
    __shared__ __align__(16) u16 ldsK[128 * 64];

    floatx4 acc[2][8];
#pragma unroll
    for (int i = 0; i < 2; ++i)
#pragma unroll
        for (int j = 0; j < 8; ++j) acc[i][j] = floatx4{0.f, 0.f, 0.f, 0.f};

    const u16* tbase = theta_sm + (size_t)n * 524288 + (size_t)st * 128 * 128;
    const u16* kbase = kvT + (size_t)n * 16384;

    for (int ch = 0; ch < 2; ++ch) {
#pragma unroll
        for (int i = 0; i < 4; ++i) {
            int op = w * 4 + i;
            int r = op * 8 + (lane >> 3);
            int lseg = (lane & 7) ^ (r & 7);
            gld16(tbase + (size_t)r * 128 + ch * 64 + lseg * 8, ldsT + op * 512);
            gld16(kbase + (size_t)r * 128 + ch * 64 + lseg * 8, ldsK + op * 512);
        }
        __syncthreads();

#pragma unroll
        for (int kk = 0; kk < 2; ++kk) {
            bf16x8 a[2];
#pragma unroll
            for (int mi = 0; mi < 2; ++mi) {
                int r = w * 32 + mi * 16 + l16;
                int phys = (kk * 4 + quad) ^ (r & 7);
                a[mi] = *(const bf16x8*)(ldsT + r * 64 + phys * 8);
            }
#pragma unroll
            for (int di = 0; di < 8; ++di) {
                int r = di * 16 + l16;
                int phys = (kk * 4 + quad) ^ (r & 7);
                bf16x8 b = *(const bf16x8*)(ldsK + r * 64 + phys * 8);
#pragma unroll
                for (int mi = 0; mi < 2; ++mi)
                    acc[mi][di] = __builtin_amdgcn_mfma_f32_16x16x32_bf16(
                        a[mi], b, acc[mi][di], 0, 0, 0);
            }
        }
        __syncthreads();
    }

#pragma unroll
    for (int mi = 0; mi < 2; ++mi)
#pragma unroll
        for (int r = 0; r < 4; ++r) {
            int s = st * 128 + w * 32 + mi * 16 + quad * 4 + r;
#pragma unroll
            for (int di = 0; di < 8; ++di)
                out_sd[(size_t)n * 524288 + (size_t)s * 128 + di * 16 + l16] =
                    f2bf(acc[mi][di][r]);
        }
}

// --------------------------------------------------------------- gemm4 ----
__device__ __forceinline__ int addsw(int seg, int s) {
    return (seg + (s & 7) + ((s >> 3) & 7)) & 7;
}

__global__ __launch_bounds__(256) void gemm4_kernel(
    const u16* __restrict__ out_sd, const u16* __restrict__ Wz,
    const float* __restrict__ shift4, const float* __restrict__ x,
    float* __restrict__ out)
{
    const int st = blockIdx.x, ot = blockIdx.y, n = blockIdx.z;
    const int tid = threadIdx.x;
    const int w = tid >> 6, lane = tid & 63;
    const int quad = lane >> 4, l16 = lane & 15;

    __shared__ __align__(16) u16 ldsY[128 * 64];
    __shared__ __align__(16) u16 ldsW[128 * 64];

    floatx4 acc[2][8];
#pragma unroll
    for (int i = 0; i < 2; ++i)
#pragma unroll
        for (int j = 0; j < 8; ++j) acc[i][j] = floatx4{0.f, 0.f, 0.f, 0.f};

    const int sl = tid & 15;
    const int cg = tid >> 4;
    const u16* ybase = out_sd + (size_t)n * 524288 + st * 128;
    unsigned int* ldsYdw = (unsigned int*)ldsY;

    u16x8 yv0[2], yv1[2];
#pragma unroll
    for (int p = 0; p < 2; ++p) {
        int c0 = 2 * cg + 32 * p;
        yv0[p] = *(const u16x8*)(ybase + (size_t)c0 * 4096 + 8 * sl);
        yv1[p] = *(const u16x8*)(ybase + (size_t)(c0 + 1) * 4096 + 8 * sl);
    }

    for (int kc = 0; kc < 2; ++kc) {
#pragma unroll
        for (int p = 0; p < 2; ++p) {
            int cp = cg + 16 * p, slog = cp >> 2, dwin = cp & 3;
#pragma unroll
            for (int j = 0; j < 8; ++j) {
                int s = 8 * sl + j;
                unsigned int pk = (unsigned int)yv0[p][j] | ((unsigned int)yv1[p][j] << 16);
                ldsYdw[s * 32 + addsw(slog, s) * 4 + dwin] = pk;
            }
        }
#pragma unroll
        for (int i = 0; i < 4; ++i) {
            int op = w * 4 + i;
            int r = op * 8 + (lane >> 3);
            int lseg = (lane & 7) ^ (r & 7);
            gld16(Wz + (size_t)(ot * 128 + r) * 128 + kc * 64 + lseg * 8, ldsW + op * 512);
        }
        if (kc < 1) {
#pragma unroll
            for (int p = 0; p < 2; ++p) {
                int c0 = 2 * cg + 32 * p;
                yv0[p] = *(const u16x8*)(ybase + (size_t)(64 + c0) * 4096 + 8 * sl);
                yv1[p] = *(const u16x8*)(ybase + (size_t)(64 + c0 + 1) * 4096 + 8 * sl);
            }
        }
        __syncthreads();

#pragma unroll
        for (int kk = 0; kk < 2; ++kk) {
            bf16x8 a[2];
#pragma unroll
            for (int mi = 0; mi < 2; ++mi) {
                int r = w * 32 + mi * 16 + l16;
                int phys = (kk * 4 + quad) ^ (r & 7);
                a[mi] = *(const bf16x8*)(ldsW + r * 64 + phys * 8);
            }
#pragma unroll
            for (int ni = 0; ni < 8; ++ni) {
                int s = ni * 16 + l16;
                int phys = addsw(kk * 4 + quad, s);
                bf16x8 b = *(const bf16x8*)(ldsY + s * 64 + phys * 8);
#pragma unroll
                for (int mi = 0; mi < 2; ++mi)
                    acc[mi][ni] = __builtin_amdgcn_mfma_f32_16x16x32_bf16(
                        a[mi], b, acc[mi][ni], 0, 0, 0);
            }
        }
        __syncthreads();
    }

#pragma unroll
    for (int mi = 0; mi < 2; ++mi)
#pragma unroll
        for (int r = 0; r < 4; ++r) {
            int o = ot * 128 + w * 32 + mi * 16 + quad * 4 + r;
            float sh = shift4[o];
#pragma unroll
            for (int ni = 0; ni < 8; ++ni) {
                int s2 = st * 128 + ni * 16 + l16;
                size_t idx = ((size_t)n * 256 + o) * 4096 + s2;
                float val = acc[mi][ni][r] + sh + x[idx];
                out[idx] = val > 0.f ? val : 0.f;
            }
        }
}

// -------------------------------------------------------------- launch ----
extern "C" void kernel_launch(void* const* d_in, const int* in_sizes, int n_in,
                              void* d_out, int out_size, void* d_ws, size_t ws_size,
                              hipStream_t stream)
{
    const float* x  = (const float*)d_in[0];
    const float* wt = (const float*)d_in[1];
    const float* wp = (const float*)d_in[2];
    const float* wg = (const float*)d_in[3];
    const float* wz = (const float*)d_in[4];
    const float* bn[16];
    for (int i = 0; i < 16; ++i) bn[i] = (const float*)d_in[5 + i];

    char* ws = (char*)d_ws;
    u16*   W1bf     = (u16*)  (ws + 0);          // 196608
    float* shift1   = (float*)(ws + 196608);     // 1536
    u16*   Wzbf     = (u16*)  (ws + 198144);     // 65536
    float* shift4   = (float*)(ws + 263680);     // 1024
    u16*   xt       = (u16*)  (ws + 264704);     // 33554432 (dead after gemm1)
    float* partials = (float*)(ws + 264704);     // 33554432 (overlays xt)
    u16*   theta_sm = (u16*)  (ws + 33819136);   // 16777216
    u16*   pg       = (u16*)  (ws + 50596352);   // 33554432 (dead after gemm2)
    u16*   out_sd   = (u16*)  (ws + 50596352);   // 16777216 (overlays pg)
    u16*   kvT      = (u16*)  (ws + 84150784 - 524288);  // 524288
    float* out = (float*)d_out;

    prep_kernel<<<384, 256, 0, stream>>>(
        wt, wp, wg, wz,
        bn[0], bn[1], bn[2], bn[3],
        bn[4], bn[5], bn[6], bn[7],
        bn[8], bn[9], bn[10], bn[11],
        bn[12], bn[13], bn[14], bn[15],
        W1bf, shift1, Wzbf, shift4);

    xt_kernel<<<dim3(64, 16), 256, 0, stream>>>(x, xt);
    gemm1_kernel<<<dim3(32, 3, 16), 256, 0, stream>>>(xt, W1bf, shift1, theta_sm, pg);
    gemm2_kernel<<<dim3(32, 16), 256, 0, stream>>>(pg, partials);
    kv_reduce_kernel<<<dim3(16, 16), 256, 0, stream>>>(partials, kvT);
    gemm3_kernel<<<dim3(32, 16), 256, 0, stream>>>(theta_sm, kvT, out_sd);
    gemm4_kernel<<<dim3(32, 2, 16), 256, 0, stream>>>(out_sd, Wzbf, shift4, x, out);
}